// Round 6
// baseline (530.492 us; speedup 1.0000x reference)
//
#include <hip/hip_runtime.h>

// VectorQuantizer: x (4,256,16,32,32) f32, weight (1024,256) f32.
// out[n*256+c] = weight[argmin_k d_np(n,k)][c], n in BTHW token order.
//
// Contract (R3, absmax 0): replicate numpy fp32 bit-for-bit:
//   sx/sw = np pairwise sumsq; m = sequential fma chain ascending c;
//   d = fl(fl(sx+sw) - 2m); argmin first-index.
// R4/R5 (passed): 3-product bf16 MFMA screen (|err| <= ~7e-5 << MARGIN=4e-4)
//   + exact resolve of near-ties (~3.5% tokens).
// R6: screen rebuilt as LDS-tiled GEMM. A-planes (64 tokens, hi+lo bf16)
//   live in 64KB LDS (xor-swizzled, conflict-free b128); acc registers held
//   across full K loop (A read once per 64x64 sub-tile, B streamed from L2);
//   gather fused into screen/resolve. xt[n][c] fp32 feeds screen staging and
//   coalesced resolve reads.

typedef __attribute__((ext_vector_type(8))) short bf16x8;
typedef __attribute__((ext_vector_type(4))) float f32x4;

#define MARGIN 4e-4f

__device__ __forceinline__ unsigned short bf16_rne(float f) {
    unsigned int u = __float_as_uint(f);
    unsigned int r = u + 0x7fffu + ((u >> 16) & 1u);
    return (unsigned short)(r >> 16);
}
__device__ __forceinline__ float bf16_to_f(unsigned short h) {
    return __uint_as_float(((unsigned int)h) << 16);
}

// ---- numpy pairwise sum of squares, n=256, contract OFF (proven R3) ----
__device__ __forceinline__ float np_sumsq_256(const float* __restrict__ p,
                                              long stride) {
#pragma clang fp contract(off)
    float half[2];
    #pragma unroll
    for (int h = 0; h < 2; ++h) {
        const float* q = p + (long)h * 128 * stride;
        float r[8];
        #pragma unroll
        for (int j = 0; j < 8; ++j) { float v = q[(long)j * stride]; r[j] = v * v; }
        for (int i = 8; i < 128; i += 8) {
            #pragma unroll
            for (int j = 0; j < 8; ++j) {
                float v = q[(long)(i + j) * stride];
                r[j] = r[j] + v * v;
            }
        }
        half[h] = ((r[0] + r[1]) + (r[2] + r[3])) + ((r[4] + r[5]) + (r[6] + r[7]));
    }
    return half[0] + half[1];
}

__global__ __launch_bounds__(256) void vq_sxq(const float* __restrict__ x,
                                              float* __restrict__ sxq) {
    const int n = blockIdx.x * 256 + threadIdx.x;
    const int b = n >> 14, thw = n & 16383;
    sxq[n] = np_sumsq_256(x + (long)b * 4194304 + thw, 16384);
}

__global__ __launch_bounds__(256) void vq_swq(const float* __restrict__ w,
                                              float* __restrict__ swq) {
    const int k = blockIdx.x * 256 + threadIdx.x;
    swq[k] = np_sumsq_256(w + (long)k * 256, 1);
}

// ---- prep_w: wt transpose + bf16 hi/lo planes + swq, one pass over w ----
__global__ __launch_bounds__(64) void vq_prep_w(const float* __restrict__ w,
                                                float* __restrict__ wt,
                                                unsigned short* __restrict__ wh,
                                                unsigned short* __restrict__ wl,
                                                float* __restrict__ swq) {
    const int k = blockIdx.x, lane = threadIdx.x;
    const float4 v = reinterpret_cast<const float4*>(w + (size_t)k * 256)[lane];
    wt[(size_t)(4 * lane + 0) * 1024 + k] = v.x;
    wt[(size_t)(4 * lane + 1) * 1024 + k] = v.y;
    wt[(size_t)(4 * lane + 2) * 1024 + k] = v.z;
    wt[(size_t)(4 * lane + 3) * 1024 + k] = v.w;
    ushort4 h, l;
    h.x = bf16_rne(v.x); l.x = bf16_rne(v.x - bf16_to_f(h.x));
    h.y = bf16_rne(v.y); l.y = bf16_rne(v.y - bf16_to_f(h.y));
    h.z = bf16_rne(v.z); l.z = bf16_rne(v.z - bf16_to_f(h.z));
    h.w = bf16_rne(v.w); l.w = bf16_rne(v.w - bf16_to_f(h.w));
    *reinterpret_cast<ushort4*>(wh + (size_t)k * 256 + 4 * lane) = h;
    *reinterpret_cast<ushort4*>(wl + (size_t)k * 256 + 4 * lane) = l;
    if (lane == 0) swq[k] = np_sumsq_256(w + (size_t)k * 256, 1);
}

// ---- xt: fp32 transpose x -> xt[n][c] (R4 split_x skeleton, fp32 out) ----
__global__ __launch_bounds__(256) void vq_xt(const float* __restrict__ x,
                                             float* __restrict__ xt) {
    __shared__ float tile[64][65];
    const int bid = blockIdx.x;
    const int b  = bid >> 10;
    const int ct = (bid >> 8) & 3;
    const int tt = bid & 255;
    const float* xb = x + (size_t)b * 4194304 + (size_t)(ct * 64) * 16384 + tt * 64;
    const int tw = threadIdx.x & 63;
    const int cg = threadIdx.x >> 6;   // 0..3
    #pragma unroll
    for (int i = 0; i < 16; i++) {
        const int cc = cg * 16 + i;
        tile[cc][tw] = xb[(size_t)cc * 16384 + tw];   // coalesced over tw
    }
    __syncthreads();
    const int c = threadIdx.x & 63;
    #pragma unroll
    for (int i = 0; i < 16; i++) {
        const int t = cg * 16 + i;
        const size_t n = (size_t)b * 16384 + tt * 64 + t;
        xt[n * 256 + ct * 64 + c] = tile[c][t];       // coalesced over c
    }
}

// ---- screen v3: LDS A-tile, acc-resident K loop, fused gather ----
// 1024 blocks x 256 thr. Block = 64 tokens; wave wv covers codes [256wv,+256).
__global__ __launch_bounds__(256, 2) void vq_screen(
        const float* __restrict__ xt,
        const unsigned short* __restrict__ wh,
        const unsigned short* __restrict__ wl,
        const float* __restrict__ swq,
        const float* __restrict__ w,
        float* __restrict__ out,
        int* __restrict__ flag,
        int* __restrict__ count) {
    __shared__ unsigned short ah_s[16384];  // 64 tokens x 256 c, swizzled
    __shared__ unsigned short al_s[16384];  // (total 64 KB; reductions alias)

    const int tid = threadIdx.x;
    const int n0 = blockIdx.x * 64;

    // stage + bf16 hi/lo split + xor-swizzle (group g -> g^(r&7))
    const float4* xt4 = reinterpret_cast<const float4*>(xt + ((size_t)n0 << 8));
    #pragma unroll
    for (int it = 0; it < 16; ++it) {
        const int i = it * 256 + tid;
        const int r = i >> 6, c4 = i & 63;
        const float4 v = xt4[(size_t)r * 64 + c4];
        ushort4 h, l;
        h.x = bf16_rne(v.x); l.x = bf16_rne(v.x - bf16_to_f(h.x));
        h.y = bf16_rne(v.y); l.y = bf16_rne(v.y - bf16_to_f(h.y));
        h.z = bf16_rne(v.z); l.z = bf16_rne(v.z - bf16_to_f(h.z));
        h.w = bf16_rne(v.w); l.w = bf16_rne(v.w - bf16_to_f(h.w));
        const int g = c4 >> 1, hf = c4 & 1;
        const int pos = r * 256 + ((g ^ (r & 7)) << 3) + (hf << 2);
        *reinterpret_cast<ushort4*>(&ah_s[pos]) = h;
        *reinterpret_cast<ushort4*>(&al_s[pos]) = l;
    }
    __syncthreads();

    const int wv = tid >> 6, lane = tid & 63;
    const int l15 = lane & 15, lq = lane >> 4;
    const int K0 = wv * 256;

    float m1[16], m2[16];
    int   i1[16];
    #pragma unroll
    for (int s = 0; s < 16; ++s) { m1[s] = 1e30f; m2[s] = 1e30f; i1[s] = 0; }

    for (int ksub = 0; ksub < 4; ++ksub) {
        f32x4 acc[4][4];
        #pragma unroll
        for (int mt = 0; mt < 4; ++mt)
            #pragma unroll
            for (int nt = 0; nt < 4; ++nt) acc[mt][nt] = (f32x4){0.f, 0.f, 0.f, 0.f};

        const int kb = K0 + ksub * 64 + l15;
        const unsigned short* bhp = wh + (size_t)kb * 256 + lq * 8;
        const unsigned short* blp = wl + (size_t)kb * 256 + lq * 8;

        for (int cs = 0; cs < 8; ++cs) {
            bf16x8 ah[4], al[4];
            #pragma unroll
            for (int mt = 0; mt < 4; ++mt) {
                const int row = mt * 16 + l15;
                const int pos = row * 256 + (((cs * 4 + lq) ^ (row & 7)) << 3);
                ah[mt] = *reinterpret_cast<const bf16x8*>(&ah_s[pos]);
                al[mt] = *reinterpret_cast<const bf16x8*>(&al_s[pos]);
            }
            #pragma unroll
            for (int nt = 0; nt < 4; ++nt) {
                const bf16x8 bh = *reinterpret_cast<const bf16x8*>(bhp + (size_t)nt * 4096 + cs * 32);
                const bf16x8 bl = *reinterpret_cast<const bf16x8*>(blp + (size_t)nt * 4096 + cs * 32);
                #pragma unroll
                for (int mt = 0; mt < 4; ++mt) {
                    acc[mt][nt] = __builtin_amdgcn_mfma_f32_16x16x32_bf16(ah[mt], bh, acc[mt][nt], 0, 0, 0);
                    acc[mt][nt] = __builtin_amdgcn_mfma_f32_16x16x32_bf16(al[mt], bh, acc[mt][nt], 0, 0, 0);
                    acc[mt][nt] = __builtin_amdgcn_mfma_f32_16x16x32_bf16(ah[mt], bl, acc[mt][nt], 0, 0, 0);
                }
            }
        }
        // scores + per-token-slot top-2 (k ascending: ksub, nt ascending)
        #pragma unroll
        for (int nt = 0; nt < 4; ++nt) {
            const int k = K0 + ksub * 64 + nt * 16 + l15;   // C/D col = l15
            const float snk = swq[k];
            #pragma unroll
            for (int mt = 0; mt < 4; ++mt)
                #pragma unroll
                for (int r = 0; r < 4; ++r) {
                    const float t = fmaf(-2.f, acc[mt][nt][r], snk);
                    const int slot = mt * 4 + r;            // token = n0+mt*16+lq*4+r
                    if (t < m1[slot]) { m2[slot] = m1[slot]; m1[slot] = t; i1[slot] = k; }
                    else               m2[slot] = fminf(m2[slot], t);
                }
        }
    }

    // merge top-2 across the 16 lanes sharing lq (xor 1,2,4,8)
    #pragma unroll
    for (int mm = 1; mm < 16; mm <<= 1) {
        #pragma unroll
        for (int s = 0; s < 16; ++s) {
            const float om1 = __shfl_xor(m1[s], mm);
            const int   oi1 = __shfl_xor(i1[s], mm);
            const float om2 = __shfl_xor(m2[s], mm);
            if (om1 < m1[s]) { m2[s] = fminf(m1[s], om2); m1[s] = om1; i1[s] = oi1; }
            else             { m2[s] = fminf(m2[s], om1); }
        }
    }

    __syncthreads();   // all LDS A-reads complete before aliasing the tile
    float* r_m1 = reinterpret_cast<float*>(ah_s);   // [4][64]
    float* r_m2 = r_m1 + 256;                       // [4][64]
    int*   r_i1 = reinterpret_cast<int*>(r_m2 + 256);
    int*   widx = r_i1 + 256;                       // [64]

    if (l15 == 0) {
        #pragma unroll
        for (int mt = 0; mt < 4; ++mt)
            #pragma unroll
            for (int r = 0; r < 4; ++r) {
                const int tok = mt * 16 + lq * 4 + r;
                r_m1[wv * 64 + tok] = m1[mt * 4 + r];
                r_m2[wv * 64 + tok] = m2[mt * 4 + r];
                r_i1[wv * 64 + tok] = i1[mt * 4 + r];
            }
    }
    __syncthreads();

    if (tid < 64) {
        float b1 = r_m1[tid], b2 = r_m2[tid];
        int   bi = r_i1[tid];
        #pragma unroll
        for (int w2 = 1; w2 < 4; ++w2) {
            const float o1 = r_m1[w2 * 64 + tid];
            const float o2 = r_m2[w2 * 64 + tid];
            const int   oi = r_i1[w2 * 64 + tid];
            if (o1 < b1) { b2 = fminf(b1, o2); b1 = o1; bi = oi; }
            else           b2 = fminf(b2, o1);
        }
        if (b2 - b1 > MARGIN) {
            widx[tid] = bi;                  // unique np-argmin, proven
        } else {
            widx[tid] = -1;
            flag[atomicAdd(count, 1)] = n0 + tid;
        }
    }
    __syncthreads();

    // fused gather for confident tokens
    const float4* w4r = reinterpret_cast<const float4*>(w);
    float4* out4 = reinterpret_cast<float4*>(out);
    #pragma unroll
    for (int it = 0; it < 16; ++it) {
        const int i = it * 256 + tid;
        const int t = i >> 6, c4 = i & 63;
        const int k = widx[t];
        if (k >= 0) out4[((size_t)(n0 + t)) * 64 + c4] = w4r[(size_t)k * 64 + c4];
    }
}

// ---- resolve v3: np-exact rescore of flagged tokens + direct out write ----
__global__ __launch_bounds__(256) void vq_resolve3(const float* __restrict__ xt,
                                                   const float* __restrict__ wt,
                                                   const float* __restrict__ w,
                                                   const float* __restrict__ sxq,
                                                   const float* __restrict__ swq,
                                                   const int* __restrict__ flag,
                                                   const int* __restrict__ count,
                                                   float* __restrict__ out) {
    __shared__ float xsh[4][256];
    __shared__ int   toks[4];
    __shared__ float r_d[4][4];
    __shared__ int   r_k[4][4];
    __shared__ int   wk[4];

    const int cnt = *count;
    const int tid = threadIdx.x;
    const int groups = (cnt + 3) >> 2;

    for (int g = blockIdx.x; g < groups; g += gridDim.x) {
        if (tid < 4) toks[tid] = (4 * g + tid < cnt) ? flag[4 * g + tid] : -1;
        __syncthreads();
        #pragma unroll
        for (int i = 0; i < 4; i++) {
            const int n = toks[i];
            xsh[i][tid] = (n >= 0) ? xt[((size_t)n << 8) + tid] : 0.f;  // coalesced
        }
        __syncthreads();

        float acc[4][4];   // [q][token]
        #pragma unroll
        for (int q = 0; q < 4; q++)
            #pragma unroll
            for (int i = 0; i < 4; i++) acc[q][i] = 0.f;

        const float* wp = wt + tid;
        #pragma unroll 4
        for (int c = 0; c < 256; c++) {    // np sgemm: ascending fma chain
            const float w0 = wp[(size_t)c * 1024 + 0];
            const float w1 = wp[(size_t)c * 1024 + 256];
            const float w2 = wp[(size_t)c * 1024 + 512];
            const float w3 = wp[(size_t)c * 1024 + 768];
            #pragma unroll
            for (int i = 0; i < 4; i++) {
                const float xc = xsh[i][c];
                acc[0][i] = fmaf(xc, w0, acc[0][i]);
                acc[1][i] = fmaf(xc, w1, acc[1][i]);
                acc[2][i] = fmaf(xc, w2, acc[2][i]);
                acc[3][i] = fmaf(xc, w3, acc[3][i]);
            }
        }

        const float swk[4] = {swq[tid], swq[tid + 256], swq[tid + 512], swq[tid + 768]};
        #pragma unroll
        for (int i = 0; i < 4; i++) {
            const int n = toks[i];
            float bd = 1e30f;
            int   bk = 0x7fffffff;
            if (n >= 0) {
                const float sx = sxq[n];
                #pragma unroll
                for (int q = 0; q < 4; q++) {
                    const int k = tid + 256 * q;
                    const float s1 = sx + swk[q];
                    const float d  = fmaf(-2.f, acc[q][i], s1);
                    if (d < bd || (d == bd && k < bk)) { bd = d; bk = k; }
                }
            }
            #pragma unroll
            for (int mm = 1; mm < 64; mm <<= 1) {
                const float od = __shfl_xor(bd, mm);
                const int   ok = __shfl_xor(bk, mm);
                if (od < bd || (od == bd && ok < bk)) { bd = od; bk = ok; }
            }
            if ((tid & 63) == 0) { r_d[tid >> 6][i] = bd; r_k[tid >> 6][i] = bk; }
        }
        __syncthreads();
        if (tid < 4) {
            float bd = r_d[0][tid]; int bk = r_k[0][tid];
            #pragma unroll
            for (int wv = 1; wv < 4; wv++) {
                const float od = r_d[wv][tid];
                const int   ok = r_k[wv][tid];
                if (od < bd || (od == bd && ok < bk)) { bd = od; bk = ok; }
            }
            wk[tid] = bk;
        }
        __syncthreads();
        {   // write rows: 4 tokens x 64 float4 = 256 threads
            const int t = tid >> 6, c4 = tid & 63;
            const int n = toks[t];
            if (n >= 0)
                reinterpret_cast<float4*>(out)[(size_t)n * 64 + c4] =
                    reinterpret_cast<const float4*>(w)[(size_t)wk[t] * 64 + c4];
        }
        __syncthreads();
    }
}

// ================= R3 fallback (proven-correct) =================
#define TPB 32
__global__ __launch_bounds__(64) void vq_wt(const float* __restrict__ w,
                                            float* __restrict__ wt) {
    const int k = blockIdx.x;
    const int lane = threadIdx.x;
    const float4 v = reinterpret_cast<const float4*>(w + (size_t)k * 256)[lane];
    wt[(size_t)(4 * lane + 0) * 1024 + k] = v.x;
    wt[(size_t)(4 * lane + 1) * 1024 + k] = v.y;
    wt[(size_t)(4 * lane + 2) * 1024 + k] = v.z;
    wt[(size_t)(4 * lane + 3) * 1024 + k] = v.w;
}

__global__ __launch_bounds__(256) void vq_main(const float* __restrict__ x,
                                               const float* __restrict__ sxq,
                                               const float* __restrict__ swq,
                                               const float* __restrict__ wt,
                                               const float* __restrict__ weight,
                                               float* __restrict__ out) {
    __shared__ __align__(16) float xs[256 * TPB];
    __shared__ float wn[1024];
    __shared__ float sxs[TPB];
    __shared__ float red_s[4][TPB];
    __shared__ int   red_i[4][TPB];
    __shared__ int   fidx[TPB];

    const int tid = threadIdx.x;
    const int n0 = blockIdx.x * TPB;
    const int b = n0 >> 14, thw = n0 & 16383;
    const float* xb = x + (size_t)b * 4194304 + thw;

    for (int i = tid; i < 256 * TPB; i += 256) {
        int t = i & (TPB - 1);
        int c = i >> 5;
        xs[c * TPB + t] = xb[(size_t)c * 16384 + t];
    }
    for (int i = tid; i < 1024; i += 256) wn[i] = swq[i];
    if (tid < TPB) sxs[tid] = sxq[n0 + tid];
    __syncthreads();

    const int lane = tid & 63, wv = tid >> 6;
    const int tg = lane & 7, cg = lane >> 3;
    float sxr[4];
    #pragma unroll
    for (int j = 0; j < 4; j++) sxr[j] = sxs[4 * tg + j];
    float bestS[4]; int bestI[4];
    #pragma unroll
    for (int j = 0; j < 4; j++) { bestS[j] = 1e30f; bestI[j] = 0x7fffffff; }

    for (int kb = 0; kb < 1024; kb += 256) {
        const int kbase = kb + 64 * wv + 8 * cg;
        float acc[4][8];
        #pragma unroll
        for (int j = 0; j < 4; j++)
            #pragma unroll
            for (int q = 0; q < 8; q++) acc[j][q] = 0.f;
        const float* wtp = wt + kbase;
        #pragma unroll 4
        for (int c = 0; c < 256; c++) {
            const float4 xv = *reinterpret_cast<const float4*>(&xs[c * TPB + 4 * tg]);
            const float4 w0 = *reinterpret_cast<const float4*>(wtp + (size_t)c * 1024);
            const float4 w1 = *reinterpret_cast<const float4*>(wtp + (size_t)c * 1024 + 4);
            const float xr[4] = {xv.x, xv.y, xv.z, xv.w};
            const float wr[8] = {w0.x, w0.y, w0.z, w0.w, w1.x, w1.y, w1.z, w1.w};
            #pragma unroll
            for (int j = 0; j < 4; j++)
                #pragma unroll
                for (int q = 0; q < 8; q++)
                    acc[j][q] = fmaf(xr[j], wr[q], acc[j][q]);
        }
        #pragma unroll
        for (int q = 0; q < 8; q++) {
            const int k = kbase + q;
            const float wnk = wn[k];
            #pragma unroll
            for (int j = 0; j < 4; j++) {
                const float s1 = sxr[j] + wnk;
                const float d = fmaf(-2.f, acc[j][q], s1);
                if (d < bestS[j]) { bestS[j] = d; bestI[j] = k; }
            }
        }
    }
    #pragma unroll
    for (int m = 8; m < 64; m <<= 1) {
        #pragma unroll
        for (int j = 0; j < 4; j++) {
            const float os = __shfl_xor(bestS[j], m);
            const int   oi = __shfl_xor(bestI[j], m);
            if (os < bestS[j] || (os == bestS[j] && oi < bestI[j])) {
                bestS[j] = os; bestI[j] = oi;
            }
        }
    }
    if (cg == 0) {
        #pragma unroll
        for (int j = 0; j < 4; j++) {
            red_s[wv][4 * tg + j] = bestS[j];
            red_i[wv][4 * tg + j] = bestI[j];
        }
    }
    __syncthreads();
    if (tid < TPB) {
        float bs = red_s[0][tid]; int bi = red_i[0][tid];
        #pragma unroll
        for (int w2 = 1; w2 < 4; w2++) {
            const float s2 = red_s[w2][tid];
            const int   i2 = red_i[w2][tid];
            if (s2 < bs || (s2 == bs && i2 < bi)) { bs = s2; bi = i2; }
        }
        fidx[tid] = bi;
    }
    __syncthreads();
    for (int i = tid; i < TPB * 256; i += 256) {
        const int t = i >> 8, c = i & 255;
        out[(size_t)(n0 + t) * 256 + c] = weight[(size_t)fidx[t] * 256 + c];
    }
}

// ================= launch =================
extern "C" void kernel_launch(void* const* d_in, const int* in_sizes, int n_in,
                              void* d_out, int out_size, void* d_ws, size_t ws_size,
                              hipStream_t stream) {
    const float* x = (const float*)d_in[0];
    const float* w = (const float*)d_in[1];
    float* out = (float*)d_out;

    char* p = (char*)d_ws;
    int*   count = (int*)p;                          p += 256;
    int*   flag  = (int*)p;                          p += 65536 * 4;
    float* sxq   = (float*)p;                        p += 65536 * 4;
    float* swq   = (float*)p;                        p += 1024 * 4;
    float* wt    = (float*)p;                        p += 262144 * 4;
    unsigned short* wh = (unsigned short*)p;         p += 262144 * 2;
    unsigned short* wl = (unsigned short*)p;         p += 262144 * 2;
    float* xt    = (float*)p;                        p += (size_t)16777216 * 4;
    const size_t need_fast = (size_t)(p - (char*)d_ws);

    if (ws_size >= need_fast) {
        hipMemsetAsync(count, 0, 4, stream);
        vq_prep_w<<<1024, 64, 0, stream>>>(w, wt, wh, wl, swq);
        vq_sxq<<<256, 256, 0, stream>>>(x, sxq);
        vq_xt<<<4096, 256, 0, stream>>>(x, xt);
        vq_screen<<<1024, 256, 0, stream>>>(xt, wh, wl, swq, w, out, flag, count);
        vq_resolve3<<<1024, 256, 0, stream>>>(xt, wt, w, sxq, swq, flag, count, out);
    } else {
        // proven R3 fallback (needs ~1.3 MB)
        float* sxq2 = (float*)d_ws;
        float* swq2 = sxq2 + 65536;
        float* wt2  = swq2 + 1024;
        vq_sxq<<<256, 256, 0, stream>>>(x, sxq2);
        vq_swq<<<4, 256, 0, stream>>>(w, swq2);
        vq_wt<<<1024, 64, 0, stream>>>(w, wt2);
        vq_main<<<65536 / TPB, 256, 0, stream>>>(x, sxq2, swq2, wt2, w, out);
    }
}